// Round 1
// baseline (69.163 us; speedup 1.0000x reference)
//
#include <hip/hip_runtime.h>

#define NS 512
#define NB 2
#define DM 512
#define NH 8
#define DH 64
#define NHDH 512                       // NH*DH
#define ATTN_SIZE (NB * NH * NS * NS)  // 4194304
#define PROJ_ELEMS (NB * NH * NS * DH) // 524288

// ---------------------------------------------------------------------------
// Pass 1: proj = query[1024x512] @ W[512x512] + bias, written in [b,h,ns,dh]
// layout. blockIdx.z = 0 -> q-proj (to d_ws), 1 -> k-proj (to k_out region,
// which is literally the second reference output).
// ---------------------------------------------------------------------------
__global__ __launch_bounds__(256) void proj_gemm(
    const float* __restrict__ query,
    const float* __restrict__ Wq, const float* __restrict__ bq,
    const float* __restrict__ Wk, const float* __restrict__ bk,
    float* __restrict__ qout, float* __restrict__ kout)
{
    const int bz = blockIdx.z;
    const float* __restrict__ Wm  = bz ? Wk : Wq;
    const float* __restrict__ bia = bz ? bk : bq;
    float* __restrict__ out = bz ? kout : qout;

    const int bx = blockIdx.x;  // head index (64-col tile == one head)
    const int by = blockIdx.y;  // 64-row tile

    __shared__ float As[16][68];  // [k][row], padded
    __shared__ float Bs[16][68];  // [k][col], padded

    const int tid = threadIdx.x;
    const int tx = tid & 15;
    const int ty = tid >> 4;

    float acc[4][4];
    #pragma unroll
    for (int i = 0; i < 4; ++i)
        #pragma unroll
        for (int j = 0; j < 4; ++j) acc[i][j] = 0.f;

    const int ar  = tid >> 2;        // 0..63 row in tile
    const int ak  = (tid & 3) * 4;   // k offset {0,4,8,12}
    const int bn  = (tid & 15) * 4;  // col offset
    const int bkk = tid >> 4;        // 0..15 k row

    for (int kt = 0; kt < 32; ++kt) {
        float4 av = *(const float4*)(query + (size_t)(by * 64 + ar) * DM + kt * 16 + ak);
        float4 bv = *(const float4*)(Wm + (size_t)(kt * 16 + bkk) * NHDH + bx * 64 + bn);
        __syncthreads();  // protect LDS from previous iteration's readers
        As[ak + 0][ar] = av.x;
        As[ak + 1][ar] = av.y;
        As[ak + 2][ar] = av.z;
        As[ak + 3][ar] = av.w;
        *(float4*)&Bs[bkk][bn] = bv;
        __syncthreads();
        #pragma unroll
        for (int k = 0; k < 16; ++k) {
            float4 a4 = *(const float4*)&As[k][ty * 4];
            float4 b4 = *(const float4*)&Bs[k][tx * 4];
            float a[4] = {a4.x, a4.y, a4.z, a4.w};
            float b[4] = {b4.x, b4.y, b4.z, b4.w};
            #pragma unroll
            for (int i = 0; i < 4; ++i)
                #pragma unroll
                for (int j = 0; j < 4; ++j) acc[i][j] = fmaf(a[i], b[j], acc[i][j]);
        }
    }

    float4 bias4 = *(const float4*)(bia + bx * 64 + tx * 4);
    float bb[4] = {bias4.x, bias4.y, bias4.z, bias4.w};
    #pragma unroll
    for (int i = 0; i < 4; ++i) {
        int r  = by * 64 + ty * 4 + i;
        int ns = r >> 1;
        int b_ = r & 1;
        float4 o;
        o.x = acc[i][0] + bb[0];
        o.y = acc[i][1] + bb[1];
        o.z = acc[i][2] + bb[2];
        o.w = acc[i][3] + bb[3];
        // out[((b*NH + h)*NS + ns)*DH + dh], h = bx, dh = tx*4..+3
        *(float4*)(out + ((size_t)(b_ * NH + bx) * NS + ns) * DH + tx * 4) = o;
    }
}

// ---------------------------------------------------------------------------
// Pass 2: attn[b,h,q,k] = 0.505*(Qdot[q]+Kdot[k]) + 0.495*sum_e w[e]*|q[e]+k[e]|
// One wave: fixed (b,h), 64 k-columns (one per lane, k-row held in 64 VGPRs),
// 16 q-rows (q values are wave-uniform -> scalar loads).
// Inner loop: 2 VALU insts per e (v_add s+v, v_fma with abs modifier).
// ---------------------------------------------------------------------------
__global__ __launch_bounds__(256) void attn_kernel(
    const float* __restrict__ qp,    // [b,h,ns,dh] (d_ws)
    const float* __restrict__ kp,    // [b,h,ns,dh] (k_out region of d_out)
    const float* __restrict__ w,     // [8,64]
    float* __restrict__ attn)        // [b,h,q,k]
{
    const int tid  = threadIdx.x;
    const int lane = tid & 63;
    const int wv   = __builtin_amdgcn_readfirstlane(tid >> 6);  // force SGPR
    const int bidx = blockIdx.x;   // 0..1023
    const int bh   = bidx >> 6;    // b*8+h
    const int rem  = bidx & 63;
    const int kb   = rem & 7;      // k-block (64 cols)
    const int qt   = rem >> 3;     // q-tile (64 rows); waves split into 16 each
    const int h    = bh & 7;

    // per-lane K row -> registers
    const float* kbase = kp + (size_t)bh * NS * DH + (size_t)(kb * 64 + lane) * DH;
    float kreg[64];
    #pragma unroll
    for (int e4 = 0; e4 < 16; ++e4) {
        float4 v = *(const float4*)(kbase + e4 * 4);
        kreg[4 * e4 + 0] = v.x;
        kreg[4 * e4 + 1] = v.y;
        kreg[4 * e4 + 2] = v.z;
        kreg[4 * e4 + 3] = v.w;
    }

    // scoring weights (wave-uniform)
    const float* wrow = w + h * DH;
    float wreg[64];
    #pragma unroll
    for (int e4 = 0; e4 < 16; ++e4) {
        float4 v = *(const float4*)(wrow + e4 * 4);
        wreg[4 * e4 + 0] = v.x;
        wreg[4 * e4 + 1] = v.y;
        wreg[4 * e4 + 2] = v.z;
        wreg[4 * e4 + 3] = v.w;
    }

    // Kdot (per lane)
    float kdot = 0.f;
    #pragma unroll
    for (int e = 0; e < 64; ++e) kdot = fmaf(wreg[e], kreg[e], kdot);

    // Qdot for this wave's 16 rows: lanes 0..15 each own one row
    const int row0 = qt * 64 + wv * 16;
    float qdml = 0.f;
    {
        const float* qr = qp + (size_t)bh * NS * DH + (size_t)(row0 + (lane & 15)) * DH;
        #pragma unroll
        for (int e = 0; e < 64; ++e) qdml = fmaf(wreg[e], qr[e], qdml);
    }

    float* obase = attn + (size_t)bh * NS * NS + (size_t)row0 * NS + kb * 64 + lane;
    const float* qbase = qp + (size_t)bh * NS * DH + (size_t)row0 * DH;

    #pragma unroll 2
    for (int r = 0; r < 16; ++r) {
        const float* qrow = qbase + r * DH;  // wave-uniform address -> s_load
        float acc = 0.f;
        #pragma unroll
        for (int e = 0; e < 64; ++e)
            acc = fmaf(wreg[e], fabsf(qrow[e] + kreg[e]), acc);
        float qd = __shfl(qdml, r);
        obase[r * NS] = fmaf(0.495f, acc, 0.505f * (qd + kdot));
    }
}

extern "C" void kernel_launch(void* const* d_in, const int* in_sizes, int n_in,
                              void* d_out, int out_size, void* d_ws, size_t ws_size,
                              hipStream_t stream) {
    const float* query = (const float*)d_in[0];
    const float* Wq    = (const float*)d_in[1];
    const float* bq    = (const float*)d_in[2];
    const float* Wk    = (const float*)d_in[3];
    const float* bk    = (const float*)d_in[4];
    const float* w     = (const float*)d_in[5];

    float* attn = (float*)d_out;                 // [2,8,512,512]
    float* kout = (float*)d_out + ATTN_SIZE;     // [16,512,64] == k-proj
    float* qws  = (float*)d_ws;                  // [16,512,64] q-proj scratch

    dim3 g1(NH, 16, 2);   // 8 head-tiles x 16 row-tiles x {q,k}
    proj_gemm<<<g1, 256, 0, stream>>>(query, Wq, bq, Wk, bk, qws, kout);

    attn_kernel<<<1024, 256, 0, stream>>>(qws, kout, w, attn);
}

// Round 2
// 49.053 us; speedup vs baseline: 1.4100x; 1.4100x over previous
//
#include <hip/hip_runtime.h>

#define NS 512
#define NB 2
#define DM 512
#define NH 8
#define DH 64
#define NHDH 512                       // NH*DH
#define ATTN_SIZE (NB * NH * NS * NS)  // 4194304

// ---------------------------------------------------------------------------
// Pass 1: proj = query[1024x512] @ W[512x512] + bias -> [b,h,ns,dh] layout.
// BM=64 (rows), BN=64 (one head), BK=32, 256 threads, 4x4 microtile.
// Register double-buffer: kt+1 global loads issued after barrier, consumed
// (via the compiler's vmcnt wait at the ds_write) a full compute phase later.
// ---------------------------------------------------------------------------
__global__ __launch_bounds__(256) void proj_gemm(
    const float* __restrict__ query,
    const float* __restrict__ Wq, const float* __restrict__ bq,
    const float* __restrict__ Wk, const float* __restrict__ bk,
    float* __restrict__ qout, float* __restrict__ kout)
{
    const int bz = blockIdx.z;
    const float* __restrict__ Wm  = bz ? Wk : Wq;
    const float* __restrict__ bia = bz ? bk : bq;
    float* __restrict__ out = bz ? kout : qout;

    const int bx = blockIdx.x;  // head (64-col tile)
    const int by = blockIdx.y;  // 64-row tile

    __shared__ float As[32][68];  // [k][row], stride 68 (2-way max on reads)
    __shared__ float Bs[32][68];  // [k][col]

    const int tid = threadIdx.x;
    const int tx = tid & 15;
    const int ty = tid >> 4;

    // staging assignment
    const int arow = tid >> 2;        // 0..63
    const int akof = (tid & 3) * 8;   // 0,8,16,24
    const int bkk  = tid >> 3;        // 0..31
    const int bcof = (tid & 7) * 8;   // 0..56

    const float* aptr = query + (size_t)(by * 64 + arow) * DM + akof;
    const float* bptr = Wm + (size_t)bkk * NHDH + bx * 64 + bcof;

    // prologue: load kt=0 tile into registers
    float4 a0 = *(const float4*)(aptr);
    float4 a1 = *(const float4*)(aptr + 4);
    float4 b0 = *(const float4*)(bptr);
    float4 b1 = *(const float4*)(bptr + 4);

    float acc[4][4];
    #pragma unroll
    for (int i = 0; i < 4; ++i)
        #pragma unroll
        for (int j = 0; j < 4; ++j) acc[i][j] = 0.f;

    for (int kt = 0; kt < 16; ++kt) {
        __syncthreads();  // previous iteration's LDS readers done
        As[akof + 0][arow] = a0.x;
        As[akof + 1][arow] = a0.y;
        As[akof + 2][arow] = a0.z;
        As[akof + 3][arow] = a0.w;
        As[akof + 4][arow] = a1.x;
        As[akof + 5][arow] = a1.y;
        As[akof + 6][arow] = a1.z;
        As[akof + 7][arow] = a1.w;
        *(float4*)&Bs[bkk][bcof]     = b0;
        *(float4*)&Bs[bkk][bcof + 4] = b1;
        __syncthreads();
        if (kt < 15) {  // issue next tile's loads; they land during compute
            const float* ap = aptr + (kt + 1) * 32;
            const float* bp = bptr + (size_t)(kt + 1) * 32 * NHDH;
            a0 = *(const float4*)(ap);
            a1 = *(const float4*)(ap + 4);
            b0 = *(const float4*)(bp);
            b1 = *(const float4*)(bp + 4);
        }
        #pragma unroll
        for (int k = 0; k < 32; ++k) {
            float4 a4 = *(const float4*)&As[k][ty * 4];
            float4 b4 = *(const float4*)&Bs[k][tx * 4];
            float a[4] = {a4.x, a4.y, a4.z, a4.w};
            float b[4] = {b4.x, b4.y, b4.z, b4.w};
            #pragma unroll
            for (int i = 0; i < 4; ++i)
                #pragma unroll
                for (int j = 0; j < 4; ++j) acc[i][j] = fmaf(a[i], b[j], acc[i][j]);
        }
    }

    float4 bias4 = *(const float4*)(bia + bx * 64 + tx * 4);
    float bb[4] = {bias4.x, bias4.y, bias4.z, bias4.w};
    #pragma unroll
    for (int i = 0; i < 4; ++i) {
        int r  = by * 64 + ty * 4 + i;
        int ns = r >> 1;
        int b_ = r & 1;
        float4 o;
        o.x = acc[i][0] + bb[0];
        o.y = acc[i][1] + bb[1];
        o.z = acc[i][2] + bb[2];
        o.w = acc[i][3] + bb[3];
        *(float4*)(out + ((size_t)(b_ * NH + bx) * NS + ns) * DH + tx * 4) = o;
    }
}

// ---------------------------------------------------------------------------
// Pass 2: attn[b,h,q,k] = 0.505*(Qdot[q]+Kdot[k]) + 0.495*sum_e w[e]*|q[e]+k[e]|
// Block = (b,h, 64 k-cols, 64 q-rows); wave wv owns 16 q-rows.
// K-tile staged TRANSPOSED in LDS [e][krow] (stride 65: <=2-way conflicts),
// Q-tile staged row-major (uniform broadcast reads). w forced into SGPRs.
// Core: 2 VALU per (q,k,e): v_add + v_fma with abs input modifier.
// ---------------------------------------------------------------------------
__global__ __launch_bounds__(256) void attn_kernel(
    const float* __restrict__ qp,    // [b,h,ns,dh] (d_ws)
    const float* __restrict__ kp,    // [b,h,ns,dh] (k_out region of d_out)
    const float* __restrict__ w,     // [8,64]
    float* __restrict__ attn)        // [b,h,q,k]
{
    __shared__ float Kt[64][65];  // [e][krow]
    __shared__ float Qs[64][68];  // [qrow][e]

    const int tid  = threadIdx.x;
    const int lane = tid & 63;
    const int wv   = __builtin_amdgcn_readfirstlane(tid >> 6);
    const int bidx = blockIdx.x;   // 0..1023
    const int bh   = bidx >> 6;    // b*8+h
    const int rem  = bidx & 63;
    const int kb   = rem & 7;      // k-block (64 cols)
    const int qt   = rem >> 3;     // q-tile (64 rows)
    const int h    = bh & 7;

    const float* ktile = kp + (size_t)bh * NS * DH + (size_t)kb * 64 * DH;  // 4096 contig
    const float* qtile = qp + (size_t)bh * NS * DH + (size_t)qt * 64 * DH;  // 4096 contig

    // cooperative coalesced staging
    #pragma unroll
    for (int rd = 0; rd < 4; ++rd) {
        int f = rd * 1024 + tid * 4;
        float4 kv = *(const float4*)(ktile + f);
        float4 qv = *(const float4*)(qtile + f);
        int e = f & 63;
        int r = f >> 6;
        Kt[e + 0][r] = kv.x;
        Kt[e + 1][r] = kv.y;
        Kt[e + 2][r] = kv.z;
        Kt[e + 3][r] = kv.w;
        *(float4*)&Qs[r][e] = qv;
    }

    // scoring weights -> SGPRs (wave-uniform)
    float wreg[64];
    #pragma unroll
    for (int e4 = 0; e4 < 16; ++e4) {
        float4 v = *(const float4*)(w + h * DH + e4 * 4);
        wreg[4 * e4 + 0] = __int_as_float(__builtin_amdgcn_readfirstlane(__float_as_int(v.x)));
        wreg[4 * e4 + 1] = __int_as_float(__builtin_amdgcn_readfirstlane(__float_as_int(v.y)));
        wreg[4 * e4 + 2] = __int_as_float(__builtin_amdgcn_readfirstlane(__float_as_int(v.z)));
        wreg[4 * e4 + 3] = __int_as_float(__builtin_amdgcn_readfirstlane(__float_as_int(v.w)));
    }

    __syncthreads();

    // per-lane K row from LDS (2-way conflicts = free), fused Kdot
    float kreg[64];
    float kd = 0.f;
    #pragma unroll
    for (int e = 0; e < 64; ++e) {
        kreg[e] = Kt[e][lane];
        kd = fmaf(wreg[e], kreg[e], kd);
    }

    // Qdot: lanes 0..15 each own one of this wave's rows
    float qdml = 0.f;
    {
        const int lr = wv * 16 + (lane & 15);
        #pragma unroll
        for (int e4 = 0; e4 < 16; ++e4) {
            float4 q4 = *(const float4*)&Qs[lr][e4 * 4];
            qdml = fmaf(wreg[4 * e4 + 0], q4.x, qdml);
            qdml = fmaf(wreg[4 * e4 + 1], q4.y, qdml);
            qdml = fmaf(wreg[4 * e4 + 2], q4.z, qdml);
            qdml = fmaf(wreg[4 * e4 + 3], q4.w, qdml);
        }
    }

    float* obase = attn + (size_t)bh * NS * NS + (size_t)(qt * 64 + wv * 16) * NS + kb * 64 + lane;

    #pragma unroll 2
    for (int r = 0; r < 16; ++r) {
        const int rr = wv * 16 + r;
        float acc = 0.f;
        #pragma unroll
        for (int e4 = 0; e4 < 16; ++e4) {
            float4 q4 = *(const float4*)&Qs[rr][e4 * 4];  // wave-uniform broadcast
            acc = fmaf(wreg[4 * e4 + 0], fabsf(q4.x + kreg[4 * e4 + 0]), acc);
            acc = fmaf(wreg[4 * e4 + 1], fabsf(q4.y + kreg[4 * e4 + 1]), acc);
            acc = fmaf(wreg[4 * e4 + 2], fabsf(q4.z + kreg[4 * e4 + 2]), acc);
            acc = fmaf(wreg[4 * e4 + 3], fabsf(q4.w + kreg[4 * e4 + 3]), acc);
        }
        float qd = __shfl(qdml, r);
        obase[r * NS] = fmaf(0.495f, acc, 0.505f * (qd + kd));
    }
}

extern "C" void kernel_launch(void* const* d_in, const int* in_sizes, int n_in,
                              void* d_out, int out_size, void* d_ws, size_t ws_size,
                              hipStream_t stream) {
    const float* query = (const float*)d_in[0];
    const float* Wq    = (const float*)d_in[1];
    const float* bq    = (const float*)d_in[2];
    const float* Wk    = (const float*)d_in[3];
    const float* bk    = (const float*)d_in[4];
    const float* w     = (const float*)d_in[5];

    float* attn = (float*)d_out;                 // [2,8,512,512]
    float* kout = (float*)d_out + ATTN_SIZE;     // [16,512,64] == k-proj (output 2)
    float* qws  = (float*)d_ws;                  // [16,512,64] q-proj scratch

    dim3 g1(NH, 16, 2);
    proj_gemm<<<g1, 256, 0, stream>>>(query, Wq, bq, Wk, bk, qws, kout);

    attn_kernel<<<1024, 256, 0, stream>>>(qws, kout, w, attn);
}

// Round 3
// 46.308 us; speedup vs baseline: 1.4935x; 1.0593x over previous
//
#include <hip/hip_runtime.h>

#define NS 512
#define NB 2
#define DM 512
#define NH 8
#define DH 64
#define NHDH 512
#define ATTN_SIZE (NB * NH * NS * NS)  // 4194304

typedef __attribute__((ext_vector_type(8))) short short8v;
typedef __attribute__((ext_vector_type(4))) float f32x4;

__device__ __forceinline__ unsigned short f2bf(float x) {
    unsigned u = __float_as_uint(x);
    u = (u + 0x7FFFu + ((u >> 16) & 1u)) >> 16;   // RNE
    return (unsigned short)u;
}

// ---------------------------------------------------------------------------
// Pass 0: query f32 -> bf16 (same layout); Wq/Wk f32 -> bf16 TRANSPOSED
// (Wt[col][k]) so pass 1 can read both operands row-major-in-K.
// blocks 0..127: query; 128..191: Wq; 192..255: Wk.
// ---------------------------------------------------------------------------
__global__ __launch_bounds__(256) void convert_kernel(
    const float* __restrict__ query,
    const float* __restrict__ Wq, const float* __restrict__ Wk,
    unsigned short* __restrict__ Xb,
    unsigned short* __restrict__ Wqt, unsigned short* __restrict__ Wkt)
{
    __shared__ __align__(16) unsigned short Ts[64][72];
    const int tid = threadIdx.x;
    const int blk = blockIdx.x;

    if (blk < 128) {
        const int base = blk * 4096 + tid * 16;
        float4 v0 = *(const float4*)(query + base);
        float4 v1 = *(const float4*)(query + base + 4);
        float4 v2 = *(const float4*)(query + base + 8);
        float4 v3 = *(const float4*)(query + base + 12);
        union { unsigned short us[8]; uint4 v; } p0, p1;
        p0.us[0] = f2bf(v0.x); p0.us[1] = f2bf(v0.y); p0.us[2] = f2bf(v0.z); p0.us[3] = f2bf(v0.w);
        p0.us[4] = f2bf(v1.x); p0.us[5] = f2bf(v1.y); p0.us[6] = f2bf(v1.z); p0.us[7] = f2bf(v1.w);
        p1.us[0] = f2bf(v2.x); p1.us[1] = f2bf(v2.y); p1.us[2] = f2bf(v2.z); p1.us[3] = f2bf(v2.w);
        p1.us[4] = f2bf(v3.x); p1.us[5] = f2bf(v3.y); p1.us[6] = f2bf(v3.z); p1.us[7] = f2bf(v3.w);
        *(uint4*)(Xb + base) = p0.v;
        *(uint4*)(Xb + base + 8) = p1.v;
        return;
    }

    const float* __restrict__ W = (blk < 192) ? Wq : Wk;
    unsigned short* __restrict__ Wt = (blk < 192) ? Wqt : Wkt;
    const int t  = (blk - 128) & 63;
    const int tr = t >> 3;   // k-tile
    const int tc = t & 7;    // col-tile

    {   // read 64x64 f32 tile, convert, store transposed in LDS
        const int r  = tid >> 2;       // row (k) in tile
        const int cq = tid & 3;        // 16-col group
        const float* src = W + (size_t)(tr * 64 + r) * NHDH + tc * 64 + cq * 16;
        #pragma unroll
        for (int v = 0; v < 4; ++v) {
            float4 a = *(const float4*)(src + v * 4);
            Ts[cq * 16 + v * 4 + 0][r] = f2bf(a.x);
            Ts[cq * 16 + v * 4 + 1][r] = f2bf(a.y);
            Ts[cq * 16 + v * 4 + 2][r] = f2bf(a.z);
            Ts[cq * 16 + v * 4 + 3][r] = f2bf(a.w);
        }
    }
    __syncthreads();
    {   // write rows of Wt (contiguous 32 B per thread)
        const int c  = tid >> 2;
        const int kq = tid & 3;
        uint4 o0 = *(const uint4*)&Ts[c][kq * 16];
        uint4 o1 = *(const uint4*)&Ts[c][kq * 16 + 8];
        unsigned short* dst = Wt + (size_t)(tc * 64 + c) * DM + tr * 64 + kq * 16;
        *(uint4*)(dst) = o0;
        *(uint4*)(dst + 8) = o1;
    }
}

// ---------------------------------------------------------------------------
// Pass 1: MFMA bf16 GEMM. C[1024,512] = Xb @ Wt^T per matrix, written to
// [b,h,ns,dh] layout. Block = 64 rows x 64 cols (one head), K-chunks of 128,
// 4 waves, each wave 32x32 via 2x2 fragments of 16x16x32, reg double-buffer.
// LDS rows padded +8 bf16 (272 B stride -> bank-quad stride 17, conflict-free).
// ---------------------------------------------------------------------------
__global__ __launch_bounds__(256) void proj_mfma(
    const unsigned short* __restrict__ Xb,
    const unsigned short* __restrict__ Wqt, const unsigned short* __restrict__ Wkt,
    const float* __restrict__ bq, const float* __restrict__ bk,
    float* __restrict__ qout, float* __restrict__ kout)
{
    const int h  = blockIdx.x;   // head = 64-col tile
    const int by = blockIdx.y;   // 64-row tile
    const int bz = blockIdx.z;
    const unsigned short* __restrict__ Wt = bz ? Wkt : Wqt;
    const float* __restrict__ bia = bz ? bk : bq;
    float* __restrict__ out = bz ? kout : qout;

    __shared__ __align__(16) unsigned short As[64][136];
    __shared__ __align__(16) unsigned short Bs[64][136];

    const int tid  = threadIdx.x;
    const int lane = tid & 63;
    const int w    = __builtin_amdgcn_readfirstlane(tid >> 6);
    const int wr   = w >> 1, wc = w & 1;
    const int l15  = lane & 15, l4 = lane >> 4;

    // prologue: chunk 0 into regs
    uint4 ra[4], rb[4];
    #pragma unroll
    for (int i = 0; i < 4; ++i) {
        int s = i * 256 + tid;
        int row = s >> 4, q = s & 15;
        ra[i] = *(const uint4*)(Xb + (size_t)(by * 64 + row) * DM + q * 8);
        rb[i] = *(const uint4*)(Wt + (size_t)(h * 64 + row) * DM + q * 8);
    }

    f32x4 acc[2][2];
    #pragma unroll
    for (int f = 0; f < 2; ++f)
        #pragma unroll
        for (int g = 0; g < 2; ++g) acc[f][g] = (f32x4){0.f, 0.f, 0.f, 0.f};

    for (int kc = 0; kc < 4; ++kc) {
        __syncthreads();
        #pragma unroll
        for (int i = 0; i < 4; ++i) {
            int s = i * 256 + tid;
            int row = s >> 4, q = s & 15;
            *(uint4*)&As[row][q * 8] = ra[i];
            *(uint4*)&Bs[row][q * 8] = rb[i];
        }
        __syncthreads();
        if (kc < 3) {
            #pragma unroll
            for (int i = 0; i < 4; ++i) {
                int s = i * 256 + tid;
                int row = s >> 4, q = s & 15;
                ra[i] = *(const uint4*)(Xb + (size_t)(by * 64 + row) * DM + (kc + 1) * 128 + q * 8);
                rb[i] = *(const uint4*)(Wt + (size_t)(h * 64 + row) * DM + (kc + 1) * 128 + q * 8);
            }
        }
        #pragma unroll
        for (int ks = 0; ks < 4; ++ks) {
            short8v a0 = *(const short8v*)&As[wr * 32 + l15     ][ks * 32 + l4 * 8];
            short8v a1 = *(const short8v*)&As[wr * 32 + 16 + l15][ks * 32 + l4 * 8];
            short8v b0 = *(const short8v*)&Bs[wc * 32 + l15     ][ks * 32 + l4 * 8];
            short8v b1 = *(const short8v*)&Bs[wc * 32 + 16 + l15][ks * 32 + l4 * 8];
            acc[0][0] = __builtin_amdgcn_mfma_f32_16x16x32_bf16(a0, b0, acc[0][0], 0, 0, 0);
            acc[0][1] = __builtin_amdgcn_mfma_f32_16x16x32_bf16(a0, b1, acc[0][1], 0, 0, 0);
            acc[1][0] = __builtin_amdgcn_mfma_f32_16x16x32_bf16(a1, b0, acc[1][0], 0, 0, 0);
            acc[1][1] = __builtin_amdgcn_mfma_f32_16x16x32_bf16(a1, b1, acc[1][1], 0, 0, 0);
        }
    }

    const float bias0 = bia[h * 64 + wc * 32 + l15];
    const float bias1 = bia[h * 64 + wc * 32 + 16 + l15];
    #pragma unroll
    for (int f = 0; f < 2; ++f)
        #pragma unroll
        for (int g = 0; g < 2; ++g) {
            float bg = g ? bias1 : bias0;
            #pragma unroll
            for (int j = 0; j < 4; ++j) {
                int rt = wr * 32 + f * 16 + l4 * 4 + j;
                int ct = wc * 32 + g * 16 + l15;
                int rg = by * 64 + rt;
                int ns_ = rg >> 1, b_ = rg & 1;
                out[((size_t)(b_ * NH + h) * NS + ns_) * DH + ct] = acc[f][g][j] + bg;
            }
        }
}

// ---------------------------------------------------------------------------
// Pass 2: attn[b,h,q,k] = 0.505*(Qdot[q]+Kdot[k]) + 0.495*sum_e w[e]*|q[e]+k[e]|
// (unchanged from R2)
// ---------------------------------------------------------------------------
__global__ __launch_bounds__(256) void attn_kernel(
    const float* __restrict__ qp,
    const float* __restrict__ kp,
    const float* __restrict__ w,
    float* __restrict__ attn)
{
    __shared__ float Kt[64][65];
    __shared__ float Qs[64][68];

    const int tid  = threadIdx.x;
    const int lane = tid & 63;
    const int wv   = __builtin_amdgcn_readfirstlane(tid >> 6);
    const int bidx = blockIdx.x;
    const int bh   = bidx >> 6;
    const int rem  = bidx & 63;
    const int kb   = rem & 7;
    const int qt   = rem >> 3;
    const int h    = bh & 7;

    const float* ktile = kp + (size_t)bh * NS * DH + (size_t)kb * 64 * DH;
    const float* qtile = qp + (size_t)bh * NS * DH + (size_t)qt * 64 * DH;

    #pragma unroll
    for (int rd = 0; rd < 4; ++rd) {
        int f = rd * 1024 + tid * 4;
        float4 kv = *(const float4*)(ktile + f);
        float4 qv = *(const float4*)(qtile + f);
        int e = f & 63;
        int r = f >> 6;
        Kt[e + 0][r] = kv.x;
        Kt[e + 1][r] = kv.y;
        Kt[e + 2][r] = kv.z;
        Kt[e + 3][r] = kv.w;
        *(float4*)&Qs[r][e] = qv;
    }

    float wreg[64];
    #pragma unroll
    for (int e4 = 0; e4 < 16; ++e4) {
        float4 v = *(const float4*)(w + h * DH + e4 * 4);
        wreg[4 * e4 + 0] = __int_as_float(__builtin_amdgcn_readfirstlane(__float_as_int(v.x)));
        wreg[4 * e4 + 1] = __int_as_float(__builtin_amdgcn_readfirstlane(__float_as_int(v.y)));
        wreg[4 * e4 + 2] = __int_as_float(__builtin_amdgcn_readfirstlane(__float_as_int(v.z)));
        wreg[4 * e4 + 3] = __int_as_float(__builtin_amdgcn_readfirstlane(__float_as_int(v.w)));
    }

    __syncthreads();

    float kreg[64];
    float kd = 0.f;
    #pragma unroll
    for (int e = 0; e < 64; ++e) {
        kreg[e] = Kt[e][lane];
        kd = fmaf(wreg[e], kreg[e], kd);
    }

    float qdml = 0.f;
    {
        const int lr = wv * 16 + (lane & 15);
        #pragma unroll
        for (int e4 = 0; e4 < 16; ++e4) {
            float4 q4 = *(const float4*)&Qs[lr][e4 * 4];
            qdml = fmaf(wreg[4 * e4 + 0], q4.x, qdml);
            qdml = fmaf(wreg[4 * e4 + 1], q4.y, qdml);
            qdml = fmaf(wreg[4 * e4 + 2], q4.z, qdml);
            qdml = fmaf(wreg[4 * e4 + 3], q4.w, qdml);
        }
    }

    float* obase = attn + (size_t)bh * NS * NS + (size_t)(qt * 64 + wv * 16) * NS + kb * 64 + lane;

    #pragma unroll 2
    for (int r = 0; r < 16; ++r) {
        const int rr = wv * 16 + r;
        float acc = 0.f;
        #pragma unroll
        for (int e4 = 0; e4 < 16; ++e4) {
            float4 q4 = *(const float4*)&Qs[rr][e4 * 4];
            acc = fmaf(wreg[4 * e4 + 0], fabsf(q4.x + kreg[4 * e4 + 0]), acc);
            acc = fmaf(wreg[4 * e4 + 1], fabsf(q4.y + kreg[4 * e4 + 1]), acc);
            acc = fmaf(wreg[4 * e4 + 2], fabsf(q4.z + kreg[4 * e4 + 2]), acc);
            acc = fmaf(wreg[4 * e4 + 3], fabsf(q4.w + kreg[4 * e4 + 3]), acc);
        }
        float qd = __shfl(qdml, r);
        obase[r * NS] = fmaf(0.495f, acc, 0.505f * (qd + kd));
    }
}

extern "C" void kernel_launch(void* const* d_in, const int* in_sizes, int n_in,
                              void* d_out, int out_size, void* d_ws, size_t ws_size,
                              hipStream_t stream) {
    const float* query = (const float*)d_in[0];
    const float* Wq    = (const float*)d_in[1];
    const float* bq    = (const float*)d_in[2];
    const float* Wk    = (const float*)d_in[3];
    const float* bk    = (const float*)d_in[4];
    const float* w     = (const float*)d_in[5];

    float* attn = (float*)d_out;
    float* kout = (float*)d_out + ATTN_SIZE;     // k-proj == output 2

    char* ws = (char*)d_ws;
    float* qws           = (float*)ws;                               // 2 MB f32 q-proj
    unsigned short* Xb   = (unsigned short*)(ws + (2u << 20));       // 1 MB bf16 query
    unsigned short* Wqt  = (unsigned short*)(ws + (3u << 20));       // 0.5 MB bf16 Wq^T
    unsigned short* Wkt  = (unsigned short*)(ws + (3u << 20) + DM * NHDH * 2);

    convert_kernel<<<256, 256, 0, stream>>>(query, Wq, Wk, Xb, Wqt, Wkt);
    proj_mfma<<<dim3(NH, 16, 2), 256, 0, stream>>>(Xb, Wqt, Wkt, bq, bk, qws, kout);
    attn_kernel<<<1024, 256, 0, stream>>>(qws, kout, w, attn);
}